// Round 5
// baseline (2712.658 us; speedup 1.0000x reference)
//
#include <hip/hip_runtime.h>
#include <hip/hip_bf16.h>
#include <math.h>

#define N_NODES 50000
#define N_EDGES 1600000
#define DIN     2000
#define HDIM    128
#define ZDIM    32
#define NBLK    768
#define NTHR    256
#define GSTRIDE (NBLK * NTHR)

// ---------------- workspace layout (bytes) ----------------
#define OFF_HA     0UL          // bf16 [N][128]
#define OFF_HB     12800000UL   // bf16 [N][128]
#define OFF_H0RES  25600000UL   // bf16 [N][128]
#define OFF_HMV    38400000UL   // bf16 [N][64]
#define OFF_W1T    44800000UL   // bf16 [128][2048]
#define OFF_W2T    45324288UL   // bf16 [128][128]
#define OFF_W3T    45357056UL   // bf16 [64][128]
#define OFF_CSRS   45373440UL   // int  [E]
#define OFF_CSRW   51773440UL   // f32  [E]
#define OFF_CNT    58173440UL
#define OFF_CNT2   58373440UL
#define OFF_OFFS   58573440UL
#define OFF_DINV   58773504UL
#define OFF_SUMSA  58973504UL
#define OFF_SUMSB  58974528UL
#define OFF_PART   58975552UL   // int [NBLK]
#define OFF_BAR    58978624UL   // int barrier counter

typedef __attribute__((ext_vector_type(8))) short short8;
typedef __attribute__((ext_vector_type(4))) float f32x4;

__device__ inline unsigned short f2bf(float f) {
    unsigned u = __builtin_bit_cast(unsigned, f);
    u += 0x7FFFu + ((u >> 16) & 1u);
    return (unsigned short)(u >> 16);
}
__device__ inline float bf2f(unsigned short u) {
    return __builtin_bit_cast(float, ((unsigned)u) << 16);
}
__device__ inline void ubf2(unsigned u, float& lo, float& hi) {
    lo = __builtin_bit_cast(float, u << 16);
    hi = __builtin_bit_cast(float, u & 0xFFFF0000u);
}
__device__ inline void unpack8(uint4 v, float* f) {
    ubf2(v.x, f[0], f[1]); ubf2(v.y, f[2], f[3]);
    ubf2(v.z, f[4], f[5]); ubf2(v.w, f[6], f[7]);
}
__device__ inline void gload_lds16(const unsigned short* g, unsigned short* l) {
    __builtin_amdgcn_global_load_lds(
        (const __attribute__((address_space(1))) unsigned int*)g,
        (__attribute__((address_space(3))) unsigned int*)l, 16, 0, 0);
}
__device__ inline f32x4 mfma16(short8 a, short8 b, f32x4 c) {
    return __builtin_amdgcn_mfma_f32_16x16x32_bf16(a, b, c, 0, 0, 0);
}

// grid barrier: monotone counter, agent scope (CG-style)
__device__ inline void gbar(int* bar, int target) {
    __threadfence();
    __syncthreads();
    if (threadIdx.x == 0) {
        __hip_atomic_fetch_add(bar, 1, __ATOMIC_RELEASE, __HIP_MEMORY_SCOPE_AGENT);
        while (__hip_atomic_load(bar, __ATOMIC_ACQUIRE, __HIP_MEMORY_SCOPE_AGENT) < target)
            __builtin_amdgcn_s_sleep(2);
    }
    __syncthreads();
    __threadfence();
}

__global__ void k_init(float* sumsA, float* sumsB, int* bar) {
    int t = threadIdx.x;
    sumsA[t] = 0.f;
    sumsB[t] = 0.f;
    if (t == 0) *bar = 0;
}

// ---- aggregation phase body: out[d] = dinv[d]*(sum w_e*h[src] + dinv[d]*h[d])
//      plus BN sum/sumsq accumulation (128 channels)
__device__ __forceinline__ void agg_phase(const unsigned short* __restrict__ h,
        unsigned short* __restrict__ out, float* __restrict__ sums,
        const int* __restrict__ offs, const int* __restrict__ csr_src,
        const float* __restrict__ csr_w, const float* __restrict__ dinv,
        char* lds) {
    const int tid = threadIdx.x;
    const int grp = tid >> 4;   // 16 groups, one row each
    const int lg = tid & 15;    // channel octet
    const int c = lg * 8;
    float ssum[8] = {}, sq[8] = {};
#pragma unroll 1
    for (int ch_ = blockIdx.x; ch_ < N_NODES / 16; ch_ += NBLK) {
        const int row = ch_ * 16 + grp;
        const float di = dinv[row];
        float a[8];
        unpack8(*(const uint4*)(h + (size_t)row * HDIM + c), a);
#pragma unroll
        for (int i = 0; i < 8; ++i) a[i] *= di;
        const int p1 = offs[row + 1];
#pragma unroll 2
        for (int p = offs[row]; p < p1; ++p) {
            int s = csr_src[p];
            float w = csr_w[p];
            float v[8];
            unpack8(*(const uint4*)(h + (size_t)s * HDIM + c), v);
#pragma unroll
            for (int i = 0; i < 8; ++i) a[i] += w * v[i];
        }
        unsigned short o[8];
#pragma unroll
        for (int i = 0; i < 8; ++i) {
            float ov = di * a[i];
            o[i] = f2bf(ov);
            ssum[i] += ov;
            sq[i] += ov * ov;
        }
        *(uint4*)(out + (size_t)row * HDIM + c) = *(const uint4*)o;
    }
    float* redS = (float*)lds;            // [16][128]
    float* redQ = (float*)(lds + 8192);   // [16][128]
#pragma unroll
    for (int i = 0; i < 8; i += 4) {
        *(float4*)&redS[grp * 128 + c + i] = *(const float4*)&ssum[i];
        *(float4*)&redQ[grp * 128 + c + i] = *(const float4*)&sq[i];
    }
    __syncthreads();
    if (tid < 128) {
        float s = 0.f, q = 0.f;
#pragma unroll
        for (int g = 0; g < 16; ++g) {
            s += redS[g * 128 + tid];
            q += redQ[g * 128 + tid];
        }
        atomicAdd(&sums[tid], s);
        atomicAdd(&sums[128 + tid], q);
    }
}

__global__ __launch_bounds__(NTHR, 4) void k_mega(
    const float* __restrict__ x, const int* __restrict__ e_src,
    const int* __restrict__ e_dst,
    const float* __restrict__ W1, const float* __restrict__ W2,
    const float* __restrict__ g1, const float* __restrict__ be1,
    const float* __restrict__ g2, const float* __restrict__ be2,
    const float* __restrict__ Wm, const float* __restrict__ bm,
    const float* __restrict__ Wv, const float* __restrict__ bv,
    const float* __restrict__ Wt, const float* __restrict__ bt,
    const float* __restrict__ eps,
    unsigned short* __restrict__ HA, unsigned short* __restrict__ HB,
    unsigned short* __restrict__ H0, unsigned short* __restrict__ HMV,
    unsigned short* __restrict__ W1t, unsigned short* __restrict__ W2t,
    unsigned short* __restrict__ W3t,
    int* __restrict__ csr_src, float* __restrict__ csr_w,
    int* __restrict__ cnt, int* __restrict__ cnt2,
    int* __restrict__ offs, float* __restrict__ dinv,
    float* __restrict__ sumsA, float* __restrict__ sumsB,
    int* __restrict__ part, int* bar,
    float* __restrict__ out_qz, float* __restrict__ out_qm,
    float* __restrict__ out_qs, float* __restrict__ out_t) {
    __shared__ __align__(16) char lds[40960];
    const int tid = threadIdx.x;
    const int bid = blockIdx.x;
    const int gtid = bid * NTHR + tid;
    const int lane = tid & 63;
    const int wave = tid >> 6;

    // ================= phase 1: weight prep + zero counters =================
#pragma unroll 1
    for (int idx = gtid; idx < 128 * 2048; idx += GSTRIDE) {
        int n = idx >> 11, k = idx & 2047;
        W1t[idx] = f2bf((k < DIN) ? W1[(size_t)k * HDIM + n] : 0.f);
    }
    if (gtid < 128 * 128) {
        int n = gtid >> 7, k = gtid & 127;
        W2t[gtid] = f2bf(W2[(size_t)k * HDIM + n]);
    }
    if (gtid < 64 * 128) {
        int n = gtid >> 7, k = gtid & 127;
        W3t[gtid] = f2bf((n < 32) ? Wm[(size_t)k * ZDIM + n]
                                  : Wv[(size_t)k * ZDIM + (n - 32)]);
    }
#pragma unroll 1
    for (int i = gtid; i < N_NODES; i += GSTRIDE) { cnt[i] = 0; cnt2[i] = 0; }
    gbar(bar, NBLK * 1);

    // ================= phase 2: degree count =================
#pragma unroll 1
    for (int e4 = gtid; e4 < N_EDGES / 4; e4 += GSTRIDE) {
        int4 d = *(const int4*)(e_dst + e4 * 4);
        atomicAdd(&cnt[d.x], 1);
        atomicAdd(&cnt[d.y], 1);
        atomicAdd(&cnt[d.z], 1);
        atomicAdd(&cnt[d.w], 1);
    }
    gbar(bar, NBLK * 2);

    // ================= phase 3: scan part A (block partials) =================
    const int CH = (N_NODES + NBLK - 1) / NBLK;  // 66
    {
        int* red = (int*)lds;          // [256]
        int* cl  = (int*)(lds + 1024); // [CH] survives barrier
        int base = bid * CH;
        int v = 0;
        if (tid < CH && base + tid < N_NODES) v = cnt[base + tid];
        if (tid < CH) cl[tid] = v;
        red[tid] = v;
        __syncthreads();
#pragma unroll
        for (int s = 128; s > 0; s >>= 1) {
            if (tid < s) red[tid] += red[tid + s];
            __syncthreads();
        }
        if (tid == 0) part[bid] = red[0];
    }
    gbar(bar, NBLK * 3);

    // ================= phase 4: scan part B (offs, dinv) =================
    {
        int* red = (int*)lds;
        int* cl  = (int*)(lds + 1024);
        int* pfx = (int*)(lds + 2048);
        int base = bid * CH;
        int s = 0;
        for (int i = tid; i < bid; i += NTHR) s += part[i];
        red[tid] = s;
        __syncthreads();
#pragma unroll
        for (int st = 128; st > 0; st >>= 1) {
            if (tid < st) red[tid] += red[tid + st];
            __syncthreads();
        }
        if (tid == 0) {
            int run = red[0];
            for (int i = 0; i < CH; ++i) { pfx[i] = run; run += cl[i]; }
        }
        __syncthreads();
        if (tid < CH && base + tid < N_NODES) {
            int idx = base + tid;
            offs[idx] = pfx[tid];
            dinv[idx] = rsqrtf((float)(cl[tid] + 1));
            if (idx == N_NODES - 1) offs[N_NODES] = pfx[tid] + cl[tid];
        }
    }
    gbar(bar, NBLK * 4);

    // ================= phase 5: CSR fill, then gemm1 =================
#pragma unroll 1
    for (int e4 = gtid; e4 < N_EDGES / 4; e4 += GSTRIDE) {
        int4 s4 = *(const int4*)(e_src + e4 * 4);
        int4 d4 = *(const int4*)(e_dst + e4 * 4);
        const int ss[4] = {s4.x, s4.y, s4.z, s4.w};
        const int dd[4] = {d4.x, d4.y, d4.z, d4.w};
#pragma unroll
        for (int q = 0; q < 4; ++q) {
            int p = atomicAdd(&cnt2[dd[q]], 1);
            int idx = offs[dd[q]] + p;
            csr_src[idx] = ss[q];
            csr_w[idx] = dinv[ss[q]];
        }
    }
    {   // gemm1: x[N,2000] f32 @ W1t -> HA bf16 [N,128]; BM=32, BK=64
        unsigned short* Abuf = (unsigned short*)lds;           // 2 * 32*64
        unsigned short* Bbuf = (unsigned short*)(lds + 8192);  // 2 * 128*64
        const int ar = tid >> 3, acp = tid & 7;
        const int rl = lane & 15, kg = lane >> 4;
        const int wn = wave * 32;
#pragma unroll 1
        for (int tile = bid; tile < (N_NODES + 31) / 32; tile += NBLK) {
            const int m0 = tile * 32;
            f32x4 acc[2][2];
#pragma unroll
            for (int i = 0; i < 2; ++i)
#pragma unroll
                for (int j = 0; j < 2; ++j) acc[i][j] = (f32x4)0.f;
            float areg[8];
            auto stageA = [&](int k0) {
                const int g = m0 + ar;
                const int kk = k0 + acp * 8;
                if (g < N_NODES && kk < DIN) {
                    *(float4*)&areg[0] = *(const float4*)(x + (size_t)g * DIN + kk);
                    *(float4*)&areg[4] = *(const float4*)(x + (size_t)g * DIN + kk + 4);
                } else {
#pragma unroll
                    for (int q = 0; q < 8; ++q) areg[q] = 0.f;
                }
            };
            auto writeA = [&](int c) {
                unsigned short u[8];
#pragma unroll
                for (int q = 0; q < 8; ++q) u[q] = f2bf(areg[q]);
                int pos = acp ^ (ar & 7);
                *(uint4*)&Abuf[c * 2048 + ar * 64 + pos * 8] = *(const uint4*)u;
            };
            auto issueB = [&](int k0, int c) {
#pragma unroll
                for (int q = 0; q < 4; ++q) {
                    int nbase = wave * 32 + q * 8;
                    int n = nbase + (lane >> 3);
                    int pos = lane & 7;
                    int ksrc = k0 + ((pos ^ (n & 7)) * 8);
                    gload_lds16(W1t + (size_t)n * 2048 + ksrc,
                                &Bbuf[c * 8192 + nbase * 64]);
                }
            };
            stageA(0);
            issueB(0, 0);
#pragma unroll 1
            for (int t = 0; t < 32; ++t) {
                const int c = t & 1;
                writeA(c);
                __syncthreads();
                if (t + 1 < 32) { stageA((t + 1) * 64); issueB((t + 1) * 64, c ^ 1); }
#pragma unroll
                for (int ks = 0; ks < 2; ++ks) {
                    short8 a[2], b[2];
                    int chv = kg + ks * 4;
#pragma unroll
                    for (int i = 0; i < 2; ++i) {
                        int r = i * 16 + rl;
                        a[i] = *(const short8*)&Abuf[c * 2048 + r * 64 + ((chv ^ (r & 7)) * 8)];
                    }
#pragma unroll
                    for (int j = 0; j < 2; ++j) {
                        int n = wn + j * 16 + rl;
                        b[j] = *(const short8*)&Bbuf[c * 8192 + n * 64 + ((chv ^ (n & 7)) * 8)];
                    }
#pragma unroll
                    for (int i = 0; i < 2; ++i)
#pragma unroll
                        for (int j = 0; j < 2; ++j)
                            acc[i][j] = mfma16(a[i], b[j], acc[i][j]);
                }
                __syncthreads();
            }
#pragma unroll
            for (int i = 0; i < 2; ++i) {
                int rb = m0 + i * 16 + (lane >> 4) * 4;
#pragma unroll
                for (int j = 0; j < 2; ++j) {
                    int col = wn + j * 16 + rl;
#pragma unroll
                    for (int r = 0; r < 4; ++r)
                        if (rb + r < N_NODES)
                            HA[(size_t)(rb + r) * HDIM + col] = f2bf(acc[i][j][r]);
                }
            }
        }
    }
    gbar(bar, NBLK * 5);

    // ================= phase 6: aggregation 1 (+BN stats) =================
    agg_phase(HA, HB, sumsA, offs, csr_src, csr_w, dinv, lds);
    gbar(bar, NBLK * 6);

    // ================= phase 7: gemm2 (bn1+relu fused; emits h0res) ========
    {
        unsigned short* As = (unsigned short*)lds;           // 32*128
        unsigned short* Bs = (unsigned short*)(lds + 8192);  // 128*128
        {   // stage W2t once
            const int br = tid >> 1, half = tid & 1;
#pragma unroll
            for (int q = 0; q < 8; ++q) {
                int ch = half * 8 + q;
                int pos = ch ^ (br & 7);
                *(uint4*)&Bs[br * 128 + pos * 8] =
                    *(const uint4*)(W2t + (size_t)br * 128 + ch * 8);
            }
        }
        __syncthreads();
        const int ar = tid >> 3, acp = tid & 7;
        const int rl = lane & 15, kg = lane >> 4;
        const int wn = wave * 32;
        const float invn = 1.f / N_NODES;
#pragma unroll 1
        for (int tile = bid; tile < (N_NODES + 31) / 32; tile += NBLK) {
            const int m0 = tile * 32;
            const int g = m0 + ar;
            const bool gok = g < N_NODES;
#pragma unroll
            for (int q = 0; q < 2; ++q) {
                int kb = acp * 16 + q * 8;
                float v[8];
                if (gok) unpack8(*(const uint4*)(HB + (size_t)g * HDIM + kb), v);
                unsigned short u[8];
#pragma unroll
                for (int e = 0; e < 8; ++e) {
                    int cc = kb + e;
                    float mean = sumsA[cc] * invn;
                    float var = sumsA[128 + cc] * invn - mean * mean;
                    float sc = g1[cc] * rsqrtf(var + 1e-5f);
                    float sh = be1[cc] - mean * sc;
                    u[e] = gok ? f2bf(fmaxf(v[e] * sc + sh, 0.f)) : (unsigned short)0;
                }
                if (gok) *(uint4*)(H0 + (size_t)g * HDIM + kb) = *(const uint4*)u;
                int ch = acp * 2 + q;
                int pos = ch ^ (ar & 7);
                *(uint4*)&As[ar * 128 + pos * 8] = *(const uint4*)u;
            }
            __syncthreads();
            f32x4 acc[2][2];
#pragma unroll
            for (int i = 0; i < 2; ++i)
#pragma unroll
                for (int j = 0; j < 2; ++j) acc[i][j] = (f32x4)0.f;
#pragma unroll
            for (int ks = 0; ks < 4; ++ks) {
                short8 a[2], b[2];
                int ch = ks * 4 + kg;
#pragma unroll
                for (int i = 0; i < 2; ++i) {
                    int r = i * 16 + rl;
                    a[i] = *(const short8*)&As[r * 128 + ((ch ^ (r & 7)) * 8)];
                }
#pragma unroll
                for (int j = 0; j < 2; ++j) {
                    int n = wn + j * 16 + rl;
                    b[j] = *(const short8*)&Bs[n * 128 + ((ch ^ (n & 7)) * 8)];
                }
#pragma unroll
                for (int i = 0; i < 2; ++i)
#pragma unroll
                    for (int j = 0; j < 2; ++j)
                        acc[i][j] = mfma16(a[i], b[j], acc[i][j]);
            }
#pragma unroll
            for (int i = 0; i < 2; ++i) {
                int rb = m0 + i * 16 + (lane >> 4) * 4;
#pragma unroll
                for (int j = 0; j < 2; ++j) {
                    int col = wn + j * 16 + rl;
#pragma unroll
                    for (int r = 0; r < 4; ++r)
                        if (rb + r < N_NODES)
                            HA[(size_t)(rb + r) * HDIM + col] = f2bf(acc[i][j][r]);
                }
            }
            __syncthreads();
        }
    }
    gbar(bar, NBLK * 7);

    // ================= phase 8: aggregation 2 (+BN stats) =================
    agg_phase(HA, HB, sumsB, offs, csr_src, csr_w, dinv, lds);
    gbar(bar, NBLK * 8);

    // ============ phase 9: gemm3 (bn2+relu+residual; hmv + t head) =========
    {
        unsigned short* As = (unsigned short*)lds;            // 32*128
        unsigned short* Bs = (unsigned short*)(lds + 8192);   // 64*128
        float* prm = (float*)(lds + 24576);                   // [256]
        float* WtS = (float*)(lds + 25600);                   // [128]
        if (tid < 128) {
            float mean = sumsB[tid] * (1.f / N_NODES);
            float var = sumsB[128 + tid] * (1.f / N_NODES) - mean * mean;
            float sc = g2[tid] * rsqrtf(var + 1e-5f);
            prm[tid] = sc;
            prm[128 + tid] = be2[tid] - mean * sc;
            WtS[tid] = Wt[tid];
        }
        {   // stage W3t once
            const int br = tid >> 2, chq = tid & 3;
#pragma unroll
            for (int q = 0; q < 4; ++q) {
                int ch = chq * 4 + q;
                int pos = ch ^ (br & 7);
                *(uint4*)&Bs[br * 128 + pos * 8] =
                    *(const uint4*)(W3t + (size_t)br * 128 + ch * 8);
            }
        }
        __syncthreads();
        const int ar = tid >> 3, acp = tid & 7;
        const int rl = lane & 15, kg = lane >> 4;
        const int wn = wave * 16;
        const float btv = bt[0];
#pragma unroll 1
        for (int tile = bid; tile < (N_NODES + 31) / 32; tile += NBLK) {
            const int m0 = tile * 32;
            const int g = m0 + ar;
            const bool gok = g < N_NODES;
#pragma unroll
            for (int q = 0; q < 2; ++q) {
                int kb = acp * 16 + q * 8;
                float v[8], rr[8];
                if (gok) {
                    unpack8(*(const uint4*)(HB + (size_t)g * HDIM + kb), v);
                    unpack8(*(const uint4*)(H0 + (size_t)g * HDIM + kb), rr);
                }
                unsigned short u[8];
#pragma unroll
                for (int e = 0; e < 8; ++e)
                    u[e] = gok ? f2bf(fmaxf(v[e] * prm[kb + e] + prm[128 + kb + e], 0.f) + rr[e])
                               : (unsigned short)0;
                int ch = acp * 2 + q;
                int pos = ch ^ (ar & 7);
                *(uint4*)&As[ar * 128 + pos * 8] = *(const uint4*)u;
            }
            __syncthreads();
            f32x4 acc[2];
            acc[0] = (f32x4)0.f;
            acc[1] = (f32x4)0.f;
#pragma unroll
            for (int ks = 0; ks < 4; ++ks) {
                short8 a[2], b;
                int ch = ks * 4 + kg;
#pragma unroll
                for (int i = 0; i < 2; ++i) {
                    int r = i * 16 + rl;
                    a[i] = *(const short8*)&As[r * 128 + ((ch ^ (r & 7)) * 8)];
                }
                int n = wn + rl;
                b = *(const short8*)&Bs[n * 128 + ((ch ^ (n & 7)) * 8)];
#pragma unroll
                for (int i = 0; i < 2; ++i) acc[i] = mfma16(a[i], b, acc[i]);
            }
#pragma unroll
            for (int i = 0; i < 2; ++i) {
                int rb = m0 + i * 16 + (lane >> 4) * 4;
                int col = wn + rl;
#pragma unroll
                for (int r = 0; r < 4; ++r)
                    if (rb + r < N_NODES)
                        HMV[(size_t)(rb + r) * 64 + col] = f2bf(acc[i][r]);
            }
            {   // t head: 8 lanes per row
                const int r = tid >> 3;
                const int sub = tid & 7;
                float s = 0.f;
#pragma unroll
                for (int q = 0; q < 2; ++q) {
                    int ch = sub * 2 + q;
                    short8 vv = *(const short8*)&As[r * 128 + ((ch ^ (r & 7)) * 8)];
#pragma unroll
                    for (int e = 0; e < 8; ++e)
                        s += bf2f((unsigned short)vv[e]) * WtS[ch * 8 + e];
                }
                s += __shfl_xor(s, 1);
                s += __shfl_xor(s, 2);
                s += __shfl_xor(s, 4);
                if (sub == 0 && (m0 + r) < N_NODES)
                    out_t[m0 + r] = 1.f / (1.f + expf(-(s + btv)));
            }
            __syncthreads();
        }
    }
    gbar(bar, NBLK * 9);

    // ================= phase 10: final aggregation + VAE epilogue ==========
    {
        const int rg = tid >> 3;   // 32 rows per iteration
        const int lg = tid & 7;
        const int c = lg * 8;
        const bool lo = lg < 4;
#pragma unroll 1
        for (int ch_ = bid; ch_ < (N_NODES + 31) / 32; ch_ += NBLK) {
            const int row = ch_ * 32 + rg;
            const bool ok = row < N_NODES;
            float a[8] = {};
            float di = 0.f;
            if (ok) {
                di = dinv[row];
                unpack8(*(const uint4*)(HMV + (size_t)row * 64 + c), a);
#pragma unroll
                for (int i = 0; i < 8; ++i) a[i] *= di;
                const int p1 = offs[row + 1];
#pragma unroll 2
                for (int p = offs[row]; p < p1; ++p) {
                    int s = csr_src[p];
                    float w = csr_w[p];
                    float v[8];
                    unpack8(*(const uint4*)(HMV + (size_t)s * 64 + c), v);
#pragma unroll
                    for (int i = 0; i < 8; ++i) a[i] += w * v[i];
                }
            }
            float qv[8];
#pragma unroll
            for (int i = 0; i < 8; ++i)
                qv[i] = di * a[i] + (lo ? bm[c + i] : bv[c - 32 + i]);
            float sp[8] = {};
            if (!lo) {
#pragma unroll
                for (int i = 0; i < 8; ++i)
                    sp[i] = fmaxf(qv[i], 0.f) + log1pf(expf(-fabsf(qv[i]))) + 1e-6f;
            }
            float spx[8];
#pragma unroll
            for (int i = 0; i < 8; ++i) spx[i] = __shfl_xor(sp[i], 4);
            if (ok) {
                if (lo) {
                    *(float4*)(out_qm + (size_t)row * 32 + c) = *(const float4*)&qv[0];
                    *(float4*)(out_qm + (size_t)row * 32 + c + 4) = *(const float4*)&qv[4];
                    float e[8];
                    *(float4*)&e[0] = *(const float4*)(eps + (size_t)row * 32 + c);
                    *(float4*)&e[4] = *(const float4*)(eps + (size_t)row * 32 + c + 4);
                    float qz[8];
#pragma unroll
                    for (int i = 0; i < 8; ++i) qz[i] = qv[i] + spx[i] * e[i];
                    *(float4*)(out_qz + (size_t)row * 32 + c) = *(const float4*)&qz[0];
                    *(float4*)(out_qz + (size_t)row * 32 + c + 4) = *(const float4*)&qz[4];
                } else {
                    *(float4*)(out_qs + (size_t)row * 32 + (c - 32)) = *(const float4*)&qv[0];
                    *(float4*)(out_qs + (size_t)row * 32 + (c - 32) + 4) = *(const float4*)&qv[4];
                }
            }
        }
    }
}

extern "C" void kernel_launch(void* const* d_in, const int* in_sizes, int n_in,
                              void* d_out, int out_size, void* d_ws, size_t ws_size,
                              hipStream_t stream) {
    (void)in_sizes; (void)n_in; (void)out_size; (void)ws_size;
    const float* x   = (const float*)d_in[0];
    const int*   ei  = (const int*)d_in[1];
    const float* W1  = (const float*)d_in[2];
    const float* W2  = (const float*)d_in[4];
    const float* g1  = (const float*)d_in[6];
    const float* be1 = (const float*)d_in[7];
    const float* g2  = (const float*)d_in[8];
    const float* be2 = (const float*)d_in[9];
    const float* Wm  = (const float*)d_in[10];
    const float* bm  = (const float*)d_in[11];
    const float* Wv  = (const float*)d_in[12];
    const float* bv  = (const float*)d_in[13];
    const float* Wt  = (const float*)d_in[14];
    const float* bt  = (const float*)d_in[15];
    const float* eps = (const float*)d_in[16];

    const int* e_src = ei;
    const int* e_dst = ei + N_EDGES;

    char* ws = (char*)d_ws;
    unsigned short* HA   = (unsigned short*)(ws + OFF_HA);
    unsigned short* HB   = (unsigned short*)(ws + OFF_HB);
    unsigned short* H0   = (unsigned short*)(ws + OFF_H0RES);
    unsigned short* HMV  = (unsigned short*)(ws + OFF_HMV);
    unsigned short* W1t  = (unsigned short*)(ws + OFF_W1T);
    unsigned short* W2t  = (unsigned short*)(ws + OFF_W2T);
    unsigned short* W3t  = (unsigned short*)(ws + OFF_W3T);
    int*   csr_src = (int*)(ws + OFF_CSRS);
    float* csr_w   = (float*)(ws + OFF_CSRW);
    int*   cnt     = (int*)(ws + OFF_CNT);
    int*   cnt2    = (int*)(ws + OFF_CNT2);
    int*   offs    = (int*)(ws + OFF_OFFS);
    float* dinv    = (float*)(ws + OFF_DINV);
    float* sumsA   = (float*)(ws + OFF_SUMSA);
    float* sumsB   = (float*)(ws + OFF_SUMSB);
    int*   part    = (int*)(ws + OFF_PART);
    int*   bar     = (int*)(ws + OFF_BAR);

    float* out_qz = (float*)d_out;
    float* out_qm = out_qz + N_NODES * ZDIM;
    float* out_qs = out_qm + N_NODES * ZDIM;
    float* out_t  = out_qs + N_NODES * ZDIM;

    k_init<<<1, 256, 0, stream>>>(sumsA, sumsB, bar);
    k_mega<<<NBLK, NTHR, 0, stream>>>(
        x, e_src, e_dst, W1, W2, g1, be1, g2, be2, Wm, bm, Wv, bv, Wt, bt, eps,
        HA, HB, H0, HMV, W1t, W2t, W3t, csr_src, csr_w, cnt, cnt2, offs, dinv,
        sumsA, sumsB, part, bar, out_qz, out_qm, out_qs, out_t);
}

// Round 6
// 636.455 us; speedup vs baseline: 4.2621x; 4.2621x over previous
//
#include <hip/hip_runtime.h>
#include <hip/hip_bf16.h>
#include <math.h>

#define N_NODES 50000
#define N_EDGES 1600000
#define DIN     2000
#define HDIM    128
#define ZDIM    32
#define AGG_GRID 782

// ---------------- workspace layout (bytes) ----------------
#define OFF_HA     0UL          // bf16 [N][128]
#define OFF_HB     12800000UL   // bf16 [N][128]
#define OFF_H0RES  25600000UL   // bf16 [N][128]
#define OFF_HMV    38400000UL   // bf16 [N][64]
#define OFF_W1T    44800000UL   // bf16 [128][2048]
#define OFF_W2T    45324288UL   // bf16 [128][128]
#define OFF_W3T    45357056UL   // bf16 [64][128]
#define OFF_CSRP   45373440UL   // int2 [E]  (packed {src, w_bits}) -> 12.8MB
#define OFF_CNT    58173440UL
#define OFF_CNT2   58373440UL
#define OFF_OFFS   58573440UL
#define OFF_DINV   58773504UL
#define OFF_SUMSA  58973504UL
#define OFF_SUMSB  58974528UL

typedef __attribute__((ext_vector_type(8))) short short8;
typedef __attribute__((ext_vector_type(4))) float f32x4;

__device__ inline unsigned short f2bf(float f) {
    unsigned u = __builtin_bit_cast(unsigned, f);
    u += 0x7FFFu + ((u >> 16) & 1u);
    return (unsigned short)(u >> 16);
}
__device__ inline float bf2f(unsigned short u) {
    return __builtin_bit_cast(float, ((unsigned)u) << 16);
}
__device__ inline void ubf2(unsigned u, float& lo, float& hi) {
    lo = __builtin_bit_cast(float, u << 16);
    hi = __builtin_bit_cast(float, u & 0xFFFF0000u);
}
__device__ inline void unpack8(uint4 v, float* f) {
    ubf2(v.x, f[0], f[1]); ubf2(v.y, f[2], f[3]);
    ubf2(v.z, f[4], f[5]); ubf2(v.w, f[6], f[7]);
}
__device__ inline void gload_lds16(const unsigned short* g, unsigned short* l) {
    __builtin_amdgcn_global_load_lds(
        (const __attribute__((address_space(1))) unsigned int*)g,
        (__attribute__((address_space(3))) unsigned int*)l, 16, 0, 0);
}
__device__ inline f32x4 mfma16(short8 a, short8 b, f32x4 c) {
    return __builtin_amdgcn_mfma_f32_16x16x32_bf16(a, b, c, 0, 0, 0);
}

// ------------- prep: weight transposes + zero counters/sums ------------------
__global__ void k_prep(const float* __restrict__ W1, const float* __restrict__ W2,
                       const float* __restrict__ Wm, const float* __restrict__ Wv,
                       unsigned short* __restrict__ W1t, unsigned short* __restrict__ W2t,
                       unsigned short* __restrict__ W3t,
                       int* __restrict__ cnt, int* __restrict__ cnt2,
                       float* __restrict__ sumsA, float* __restrict__ sumsB) {
    int b = blockIdx.x;
    int tid = threadIdx.x;
    if (b < 1024) {                       // W1t: 128 x 2048
        int idx = b * 256 + tid;
        int n = idx >> 11, k = idx & 2047;
        W1t[idx] = f2bf((k < DIN) ? W1[(size_t)k * HDIM + n] : 0.f);
    } else if (b < 1088) {                // W2t: 128 x 128 (transposed)
        int idx = (b - 1024) * 256 + tid;
        int n = idx >> 7, k = idx & 127;
        W2t[idx] = f2bf(W2[(size_t)k * HDIM + n]);
    } else if (b < 1120) {                // W3t: 64 x 128 ([Wm|Wv] transposed)
        int idx = (b - 1088) * 256 + tid;
        int n = idx >> 7, k = idx & 127;
        W3t[idx] = f2bf((n < 32) ? Wm[(size_t)k * ZDIM + n]
                                 : Wv[(size_t)k * ZDIM + (n - 32)]);
    } else if (b < 1316) {                // zero cnt, cnt2
        int idx = (b - 1120) * 256 + tid;
        if (idx < N_NODES) { cnt[idx] = 0; cnt2[idx] = 0; }
    } else if (b == 1316) {
        sumsA[tid] = 0.f;
    } else {
        sumsB[tid] = 0.f;
    }
}

// ---------------- CSR build ----------------
__global__ void k_count(const int* __restrict__ dst, int* __restrict__ cnt) {
    int e4 = blockIdx.x * blockDim.x + threadIdx.x;
    if (e4 >= N_EDGES / 4) return;
    int4 d = *(const int4*)(dst + e4 * 4);
    atomicAdd(&cnt[d.x], 1);
    atomicAdd(&cnt[d.y], 1);
    atomicAdd(&cnt[d.z], 1);
    atomicAdd(&cnt[d.w], 1);
}

__global__ void k_scan(const int* __restrict__ cnt, int* __restrict__ offs,
                       float* __restrict__ dinv) {
    __shared__ int sums[1024];
    const int CH = (N_NODES + 1023) / 1024;
    int t = threadIdx.x;
    int base = t * CH;
    int s = 0;
    for (int i = 0; i < CH; ++i) {
        int idx = base + i;
        if (idx < N_NODES) s += cnt[idx];
    }
    sums[t] = s;
    __syncthreads();
    for (int d = 1; d < 1024; d <<= 1) {
        int v = sums[t];
        int add = (t >= d) ? sums[t - d] : 0;
        __syncthreads();
        sums[t] = v + add;
        __syncthreads();
    }
    int run = (t == 0) ? 0 : sums[t - 1];
    for (int i = 0; i < CH; ++i) {
        int idx = base + i;
        if (idx < N_NODES) {
            offs[idx] = run;
            int c = cnt[idx];
            run += c;
            dinv[idx] = rsqrtf((float)(c + 1));
        }
    }
    if (t == 1023) offs[N_NODES] = run;
}

__global__ void k_fill(const int* __restrict__ src, const int* __restrict__ dst,
                       const int* __restrict__ offs, int* __restrict__ cnt2,
                       const float* __restrict__ dinv, int2* __restrict__ csrp) {
    int e4 = blockIdx.x * blockDim.x + threadIdx.x;
    if (e4 >= N_EDGES / 4) return;
    int4 s4 = *(const int4*)(src + e4 * 4);
    int4 d4 = *(const int4*)(dst + e4 * 4);
    const int ss[4] = {s4.x, s4.y, s4.z, s4.w};
    const int dd[4] = {d4.x, d4.y, d4.z, d4.w};
#pragma unroll
    for (int q = 0; q < 4; ++q) {
        int p = atomicAdd(&cnt2[dd[q]], 1);
        csrp[offs[dd[q]] + p] = make_int2(ss[q], __float_as_int(dinv[ss[q]]));
    }
}

// ---------------- gemm1: x[N,2000](f32) @ W1 -> bf16 [N,128], MFMA ----------
#define G1_BM 64
#define G1_BK 64
__global__ __launch_bounds__(256) void k_gemm1m(const float* __restrict__ A,
                                                const unsigned short* __restrict__ Bt,
                                                unsigned short* __restrict__ C) {
    __shared__ __align__(16) unsigned short Abuf[2][G1_BM * G1_BK];
    __shared__ __align__(16) unsigned short Bbuf[2][HDIM * G1_BK];
    const int tid  = threadIdx.x;
    const int lane = tid & 63;
    const int wave = tid >> 6;
    const int m0   = blockIdx.x * G1_BM;
    const int wm   = (wave >> 1) * 32;
    const int wn   = (wave & 1) * 64;
    const int ar   = tid >> 2;
    const int acp  = tid & 3;

    f32x4 acc[2][4];
#pragma unroll
    for (int i = 0; i < 2; ++i)
#pragma unroll
        for (int j = 0; j < 4; ++j) acc[i][j] = (f32x4)0.f;

    float areg[16];

    auto stageA = [&](int k0) {
        const int g = m0 + ar;
        const int kk = k0 + acp * 16;
        if (g < N_NODES && kk < DIN) {
#pragma unroll
            for (int q = 0; q < 4; ++q)
                *(float4*)&areg[q * 4] = *(const float4*)(A + (size_t)g * DIN + kk + q * 4);
        } else {
#pragma unroll
            for (int q = 0; q < 16; ++q) areg[q] = 0.f;
        }
    };

    auto writeA = [&](int c) {
        unsigned short u[16];
#pragma unroll
        for (int q = 0; q < 16; ++q) u[q] = f2bf(areg[q]);
#pragma unroll
        for (int q = 0; q < 2; ++q) {
            int chunk = acp * 2 + q;
            int pos = chunk ^ (ar & 7);
            *(uint4*)&Abuf[c][ar * G1_BK + pos * 8] = *(const uint4*)&u[q * 8];
        }
    };

    auto issueB = [&](int k0, int c) {
#pragma unroll
        for (int q = 0; q < 4; ++q) {
            int nbase = wave * 32 + q * 8;
            int n = nbase + (lane >> 3);
            int pos = lane & 7;
            int ksrc = k0 + ((pos ^ (n & 7)) * 8);
            gload_lds16(Bt + (size_t)n * 2048 + ksrc, &Bbuf[c][nbase * G1_BK]);
        }
    };

    auto compute = [&](int c) {
        const int rl = lane & 15;
        const int kg = lane >> 4;
#pragma unroll
        for (int ks = 0; ks < 2; ++ks) {
            short8 a[2], b[4];
#pragma unroll
            for (int i = 0; i < 2; ++i) {
                int r = wm + i * 16 + rl;
                int pos = (kg + ks * 4) ^ (r & 7);
                a[i] = *(const short8*)&Abuf[c][r * G1_BK + pos * 8];
            }
#pragma unroll
            for (int j = 0; j < 4; ++j) {
                int n = wn + j * 16 + rl;
                int pos = (kg + ks * 4) ^ (n & 7);
                b[j] = *(const short8*)&Bbuf[c][n * G1_BK + pos * 8];
            }
#pragma unroll
            for (int i = 0; i < 2; ++i)
#pragma unroll
                for (int j = 0; j < 4; ++j)
                    acc[i][j] = mfma16(a[i], b[j], acc[i][j]);
        }
    };

    const int NT = 32;
    stageA(0);
    issueB(0, 0);
#pragma unroll 1
    for (int t = 0; t < NT; ++t) {
        const int c = t & 1;
        writeA(c);
        __syncthreads();
        if (t + 1 < NT) { stageA((t + 1) * G1_BK); issueB((t + 1) * G1_BK, c ^ 1); }
        compute(c);
        __syncthreads();
    }
#pragma unroll
    for (int i = 0; i < 2; ++i) {
        int rb = m0 + wm + i * 16 + (lane >> 4) * 4;
#pragma unroll
        for (int j = 0; j < 4; ++j) {
            int col = wn + j * 16 + (lane & 15);
#pragma unroll
            for (int r = 0; r < 4; ++r)
                if (rb + r < N_NODES) C[(size_t)(rb + r) * HDIM + col] = f2bf(acc[i][j][r]);
        }
    }
}

// ---- aggregation (128 ch): 32 lanes/row = 2 edge-teams, chunk-4 prefetch ----
__global__ __launch_bounds__(256) void k_aggs(const unsigned short* __restrict__ h,
        const int* __restrict__ offs, const int2* __restrict__ csrp,
        const float* __restrict__ dinv,
        unsigned short* __restrict__ out, float* __restrict__ sums) {
    __shared__ float redS[8][128];
    __shared__ float redQ[8][128];
    const int tid = threadIdx.x;
    const int slot = tid >> 5;      // 8 row slots
    const int l32 = tid & 31;
    const int team = l32 >> 4;      // 0/1: even/odd edges
    const int lg = l32 & 15;        // channel octet
    const int c = lg * 8;
    float ssum[8] = {}, sq[8] = {};
#pragma unroll 1
    for (int base = blockIdx.x * 8; base < N_NODES; base += AGG_GRID * 8) {
        const int row = base + slot;
        if (row >= N_NODES) continue;
        const float di = dinv[row];
        float a[8] = {};
        if (team == 0) {
            float hv[8];
            unpack8(*(const uint4*)(h + (size_t)row * HDIM + c), hv);
#pragma unroll
            for (int i = 0; i < 8; ++i) a[i] = di * hv[i];
        }
        const int p1 = offs[row + 1];
        int p = offs[row] + team;
#pragma unroll 1
        for (; p + 6 < p1; p += 8) {   // 4 edges per team per chunk (stride 2)
            int2 e0 = csrp[p];
            int2 e1 = csrp[p + 2];
            int2 e2 = csrp[p + 4];
            int2 e3 = csrp[p + 6];
            uint4 g0 = *(const uint4*)(h + (size_t)e0.x * HDIM + c);
            uint4 g1 = *(const uint4*)(h + (size_t)e1.x * HDIM + c);
            uint4 g2 = *(const uint4*)(h + (size_t)e2.x * HDIM + c);
            uint4 g3 = *(const uint4*)(h + (size_t)e3.x * HDIM + c);
            float w0 = __int_as_float(e0.y), w1 = __int_as_float(e1.y);
            float w2 = __int_as_float(e2.y), w3 = __int_as_float(e3.y);
            float v[8];
            unpack8(g0, v);
#pragma unroll
            for (int i = 0; i < 8; ++i) a[i] += w0 * v[i];
            unpack8(g1, v);
#pragma unroll
            for (int i = 0; i < 8; ++i) a[i] += w1 * v[i];
            unpack8(g2, v);
#pragma unroll
            for (int i = 0; i < 8; ++i) a[i] += w2 * v[i];
            unpack8(g3, v);
#pragma unroll
            for (int i = 0; i < 8; ++i) a[i] += w3 * v[i];
        }
#pragma unroll 1
        for (; p < p1; p += 2) {
            int2 e = csrp[p];
            uint4 g = *(const uint4*)(h + (size_t)e.x * HDIM + c);
            float w = __int_as_float(e.y);
            float v[8];
            unpack8(g, v);
#pragma unroll
            for (int i = 0; i < 8; ++i) a[i] += w * v[i];
        }
#pragma unroll
        for (int i = 0; i < 8; ++i) a[i] += __shfl_xor(a[i], 16);
        if (team == 0) {
            unsigned short o[8];
#pragma unroll
            for (int i = 0; i < 8; ++i) {
                float ov = di * a[i];
                o[i] = f2bf(ov);
                ssum[i] += ov;
                sq[i] += ov * ov;
            }
            *(uint4*)(out + (size_t)row * HDIM + c) = *(const uint4*)o;
        }
    }
    if (team == 0) {
#pragma unroll
        for (int i = 0; i < 8; i += 4) {
            *(float4*)&redS[slot][c + i] = *(const float4*)&ssum[i];
            *(float4*)&redQ[slot][c + i] = *(const float4*)&sq[i];
        }
    }
    __syncthreads();
    if (tid < 128) {
        float s = 0.f, q = 0.f;
#pragma unroll
        for (int g = 0; g < 8; ++g) { s += redS[g][tid]; q += redQ[g][tid]; }
        atomicAdd(&sums[tid], s);
        atomicAdd(&sums[128 + tid], q);
    }
}

// ------- gemm2: params from sums; h0 = relu(bn(agg0)); h1 = h0 @ W2 ---------
__global__ __launch_bounds__(256) void k_gemm2m(const unsigned short* __restrict__ Ain,
        const unsigned short* __restrict__ W2t, const float* __restrict__ sums,
        const float* __restrict__ gg, const float* __restrict__ beta,
        unsigned short* __restrict__ h0res, unsigned short* __restrict__ Hout) {
    __shared__ __align__(16) unsigned short As[64 * 128];
    __shared__ __align__(16) unsigned short Bs[128 * 128];
    __shared__ float prm[256];
    const int tid = threadIdx.x, lane = tid & 63, wave = tid >> 6;
    const int m0 = blockIdx.x * 64;
    if (tid < 128) {
        float mean = sums[tid] * (1.f / N_NODES);
        float var = sums[128 + tid] * (1.f / N_NODES) - mean * mean;
        float rstd = rsqrtf(var + 1e-5f);
        float sc = gg[tid] * rstd;
        prm[tid] = sc;
        prm[128 + tid] = beta[tid] - mean * sc;
    }
    __syncthreads();
    {   // stage A with BN+ReLU, emit h0res
        const int ar = tid >> 2, acp = tid & 3;
        const int g = m0 + ar;
        unsigned short u[32];
        if (g < N_NODES) {
#pragma unroll
            for (int q = 0; q < 4; ++q) {
                int kb = acp * 32 + q * 8;
                float v[8];
                unpack8(*(const uint4*)(Ain + (size_t)g * HDIM + kb), v);
#pragma unroll
                for (int e = 0; e < 8; ++e)
                    u[q * 8 + e] = f2bf(fmaxf(v[e] * prm[kb + e] + prm[128 + kb + e], 0.f));
            }
#pragma unroll
            for (int q = 0; q < 4; ++q)
                *(uint4*)(h0res + (size_t)g * HDIM + acp * 32 + q * 8) = *(const uint4*)&u[q * 8];
        } else {
#pragma unroll
            for (int q = 0; q < 32; ++q) u[q] = 0;
        }
#pragma unroll
        for (int q = 0; q < 4; ++q) {
            int ch = acp * 4 + q;
            int pos = ch ^ (ar & 7);
            *(uint4*)&As[ar * 128 + pos * 8] = *(const uint4*)&u[q * 8];
        }
    }
    {   // stage B (W2t [n][k]) swizzled
        const int br = tid >> 1, half = tid & 1;
#pragma unroll
        for (int q = 0; q < 8; ++q) {
            int ch = half * 8 + q;
            int pos = ch ^ (br & 7);
            *(uint4*)&Bs[br * 128 + pos * 8] =
                *(const uint4*)(W2t + (size_t)br * 128 + ch * 8);
        }
    }
    __syncthreads();
    const int wm = (wave >> 1) * 32, wn = (wave & 1) * 64;
    const int rl = lane & 15, kg = lane >> 4;
    f32x4 acc[2][4];
#pragma unroll
    for (int i = 0; i < 2; ++i)
#pragma unroll
        for (int j = 0; j < 4; ++j) acc[i][j] = (f32x4)0.f;
#pragma unroll
    for (int ks = 0; ks < 4; ++ks) {
        short8 a[2], b[4];
        int ch = ks * 4 + kg;
#pragma unroll
        for (int i = 0; i < 2; ++i) {
            int r = wm + i * 16 + rl;
            a[i] = *(const short8*)&As[r * 128 + (ch ^ (r & 7)) * 8];
        }
#pragma unroll
        for (int j = 0; j < 4; ++j) {
            int n = wn + j * 16 + rl;
            b[j] = *(const short8*)&Bs[n * 128 + (ch ^ (n & 7)) * 8];
        }
#pragma unroll
        for (int i = 0; i < 2; ++i)
#pragma unroll
            for (int j = 0; j < 4; ++j) acc[i][j] = mfma16(a[i], b[j], acc[i][j]);
    }
#pragma unroll
    for (int i = 0; i < 2; ++i) {
        int rb = m0 + wm + i * 16 + (lane >> 4) * 4;
#pragma unroll
        for (int j = 0; j < 4; ++j) {
            int col = wn + j * 16 + rl;
#pragma unroll
            for (int r = 0; r < 4; ++r)
                if (rb + r < N_NODES) Hout[(size_t)(rb + r) * HDIM + col] = f2bf(acc[i][j][r]);
        }
    }
}

// -- gemm3: params from sums; h = relu(bn(agg1))+h0res; hmv = h@[Wm|Wv]; t-head
__global__ __launch_bounds__(256) void k_gemm3m(const unsigned short* __restrict__ Ain,
        const unsigned short* __restrict__ h0res, const float* __restrict__ sums,
        const float* __restrict__ gg, const float* __restrict__ beta,
        const unsigned short* __restrict__ W3t, const float* __restrict__ Wt,
        const float* __restrict__ bt,
        unsigned short* __restrict__ hmv, float* __restrict__ t_out) {
    __shared__ __align__(16) unsigned short As[64 * 128];
    __shared__ __align__(16) unsigned short Bs[64 * 128];
    __shared__ float WtS[128];
    __shared__ float prm[256];
    const int tid = threadIdx.x, lane = tid & 63, wave = tid >> 6;
    const int m0 = blockIdx.x * 64;
    if (tid < 128) {
        float mean = sums[tid] * (1.f / N_NODES);
        float var = sums[128 + tid] * (1.f / N_NODES) - mean * mean;
        float rstd = rsqrtf(var + 1e-5f);
        float sc = gg[tid] * rstd;
        prm[tid] = sc;
        prm[128 + tid] = beta[tid] - mean * sc;
        WtS[tid] = Wt[tid];
    }
    __syncthreads();
    {   // stage A: relu(bn(agg1)) + h0res
        const int ar = tid >> 2, acp = tid & 3;
        const int g = m0 + ar;
        unsigned short u[32];
        if (g < N_NODES) {
#pragma unroll
            for (int q = 0; q < 4; ++q) {
                int kb = acp * 32 + q * 8;
                float v[8], rr[8];
                unpack8(*(const uint4*)(Ain + (size_t)g * HDIM + kb), v);
                unpack8(*(const uint4*)(h0res + (size_t)g * HDIM + kb), rr);
#pragma unroll
                for (int e = 0; e < 8; ++e)
                    u[q * 8 + e] =
                        f2bf(fmaxf(v[e] * prm[kb + e] + prm[128 + kb + e], 0.f) + rr[e]);
            }
        } else {
#pragma unroll
            for (int q = 0; q < 32; ++q) u[q] = 0;
        }
#pragma unroll
        for (int q = 0; q < 4; ++q) {
            int ch = acp * 4 + q;
            int pos = ch ^ (ar & 7);
            *(uint4*)&As[ar * 128 + pos * 8] = *(const uint4*)&u[q * 8];
        }
    }
    {   // stage B (W3t [64][128]) swizzled
        const int br = tid >> 2, chq = tid & 3;
#pragma unroll
        for (int q = 0; q < 4; ++q) {
            int ch = chq * 4 + q;
            int pos = ch ^ (br & 7);
            *(uint4*)&Bs[br * 128 + pos * 8] =
                *(const uint4*)(W3t + (size_t)br * 128 + ch * 8);
        }
    }
    __syncthreads();
    const int wm = (wave >> 1) * 32, wn = (wave & 1) * 32;
    const int rl = lane & 15, kg = lane >> 4;
    f32x4 acc[2][2];
#pragma unroll
    for (int i = 0; i < 2; ++i)
#pragma unroll
        for (int j = 0; j < 2; ++j) acc[i][j] = (f32x4)0.f;
#pragma unroll
    for (int ks = 0; ks < 4; ++ks) {
        short8 a[2], b[2];
        int ch = ks * 4 + kg;
#pragma unroll
        for (int i = 0; i < 2; ++i) {
            int r = wm + i * 16 + rl;
            a[i] = *(const short8*)&As[r * 128 + (ch ^ (r & 7)) * 8];
        }
#pragma unroll
        for (int j = 0; j < 2; ++j) {
            int n = wn + j * 16 + rl;
            b[j] = *(const short8*)&Bs[n * 128 + (ch ^ (n & 7)) * 8];
        }
#pragma unroll
        for (int i = 0; i < 2; ++i)
#pragma unroll
            for (int j = 0; j < 2; ++j) acc[i][j] = mfma16(a[i], b[j], acc[i][j]);
    }
#pragma unroll
    for (int i = 0; i < 2; ++i) {
        int rb = m0 + wm + i * 16 + (lane >> 4) * 4;
#pragma unroll
        for (int j = 0; j < 2; ++j) {
            int col = wn + j * 16 + rl;
#pragma unroll
            for (int r = 0; r < 4; ++r)
                if (rb + r < N_NODES) hmv[(size_t)(rb + r) * 64 + col] = f2bf(acc[i][j][r]);
        }
    }
    {   // t-head
        const int r = wave * 16 + (lane & 15);
        const int sub = lane >> 4;
        float s = 0.f;
#pragma unroll
        for (int q = 0; q < 4; ++q) {
            int ch = sub * 4 + q;
            short8 v = *(const short8*)&As[r * 128 + (ch ^ (r & 7)) * 8];
#pragma unroll
            for (int e = 0; e < 8; ++e)
                s += bf2f((unsigned short)v[e]) * WtS[ch * 8 + e];
        }
        s += __shfl_xor(s, 16);
        s += __shfl_xor(s, 32);
        if (sub == 0 && (m0 + r) < N_NODES)
            t_out[m0 + r] = 1.f / (1.f + expf(-(s + bt[0])));
    }
}

// ---- final aggregation (64 ch): 16 lanes/row = 2 teams, chunk-4 prefetch ----
__global__ __launch_bounds__(256) void k_aggfin5(const unsigned short* __restrict__ hmv,
        const int* __restrict__ offs, const int2* __restrict__ csrp,
        const float* __restrict__ dinv,
        const float* __restrict__ bm, const float* __restrict__ bv,
        const float* __restrict__ eps,
        float* __restrict__ out_qz, float* __restrict__ out_qm,
        float* __restrict__ out_qs) {
    const int tid = threadIdx.x;
    const int slot = tid >> 4;      // 16 row slots
    const int l16 = tid & 15;
    const int team = l16 >> 3;
    const int l = l16 & 7;
    const int c = l * 8;
#pragma unroll 1
    for (int base = blockIdx.x * 16; base < N_NODES; base += AGG_GRID * 16) {
        const int row = base + slot;
        if (row >= N_NODES) continue;
        const float di = dinv[row];
        float a[8] = {};
        if (team == 0) {
            float hv[8];
            unpack8(*(const uint4*)(hmv + (size_t)row * 64 + c), hv);
#pragma unroll
            for (int i = 0; i < 8; ++i) a[i] = di * hv[i];
        }
        const int p1 = offs[row + 1];
        int p = offs[row] + team;
#pragma unroll 1
        for (; p + 6 < p1; p += 8) {
            int2 e0 = csrp[p];
            int2 e1 = csrp[p + 2];
            int2 e2 = csrp[p + 4];
            int2 e3 = csrp[p + 6];
            uint4 g0 = *(const uint4*)(hmv + (size_t)e0.x * 64 + c);
            uint4 g1 = *(const uint4*)(hmv + (size_t)e1.x * 64 + c);
            uint4 g2 = *(const uint4*)(hmv + (size_t)e2.x * 64 + c);
            uint4 g3 = *(const uint4*)(hmv + (size_t)e3.x * 64 + c);
            float w0 = __int_as_float(e0.y), w1 = __int_as_float(e1.y);
            float w2 = __int_as_float(e2.y), w3 = __int_as_float(e3.y);
            float v[8];
            unpack8(g0, v);
#pragma unroll
            for (int i = 0; i < 8; ++i) a[i] += w0 * v[i];
            unpack8(g1, v);
#pragma unroll
            for (int i = 0; i < 8; ++i) a[i] += w1 * v[i];
            unpack8(g2, v);
#pragma unroll
            for (int i = 0; i < 8; ++i) a[i] += w2 * v[i];
            unpack8(g3, v);
#pragma unroll
            for (int i = 0; i < 8; ++i) a[i] += w3 * v[i];
        }
#pragma unroll 1
        for (; p < p1; p += 2) {
            int2 e = csrp[p];
            uint4 g = *(const uint4*)(hmv + (size_t)e.x * 64 + c);
            float w = __int_as_float(e.y);
            float v[8];
            unpack8(g, v);
#pragma unroll
            for (int i = 0; i < 8; ++i) a[i] += w * v[i];
        }
#pragma unroll
        for (int i = 0; i < 8; ++i) a[i] += __shfl_xor(a[i], 8);
        // epilogue (team 0 lanes hold full sums for channels c..c+7)
        const bool lo = l < 4;
        float qv[8];
#pragma unroll
        for (int i = 0; i < 8; ++i)
            qv[i] = di * a[i] + (lo ? bm[c + i] : bv[c - 32 + i]);
        float sp[8] = {};
        if (!lo) {
#pragma unroll
            for (int i = 0; i < 8; ++i)
                sp[i] = fmaxf(qv[i], 0.f) + log1pf(expf(-fabsf(qv[i]))) + 1e-6f;
        }
        float spx[8];
#pragma unroll
        for (int i = 0; i < 8; ++i) spx[i] = __shfl_xor(sp[i], 4);
        if (team == 0) {
            if (lo) {
                *(float4*)(out_qm + (size_t)row * 32 + c) = *(const float4*)&qv[0];
                *(float4*)(out_qm + (size_t)row * 32 + c + 4) = *(const float4*)&qv[4];
                float e[8];
                *(float4*)&e[0] = *(const float4*)(eps + (size_t)row * 32 + c);
                *(float4*)&e[4] = *(const float4*)(eps + (size_t)row * 32 + c + 4);
                float qz[8];
#pragma unroll
                for (int i = 0; i < 8; ++i) qz[i] = qv[i] + spx[i] * e[i];
                *(float4*)(out_qz + (size_t)row * 32 + c) = *(const float4*)&qz[0];
                *(float4*)(out_qz + (size_t)row * 32 + c + 4) = *(const float4*)&qz[4];
            } else {
                *(float4*)(out_qs + (size_t)row * 32 + (c - 32)) = *(const float4*)&qv[0];
                *(float4*)(out_qs + (size_t)row * 32 + (c - 32) + 4) = *(const float4*)&qv[4];
            }
        }
    }
}

extern "C" void kernel_launch(void* const* d_in, const int* in_sizes, int n_in,
                              void* d_out, int out_size, void* d_ws, size_t ws_size,
                              hipStream_t stream) {
    (void)in_sizes; (void)n_in; (void)out_size; (void)ws_size;
    const float* x   = (const float*)d_in[0];
    const int*   ei  = (const int*)d_in[1];
    const float* W1  = (const float*)d_in[2];
    const float* W2  = (const float*)d_in[4];
    const float* g1  = (const float*)d_in[6];
    const float* be1 = (const float*)d_in[7];
    const float* g2  = (const float*)d_in[8];
    const float* be2 = (const float*)d_in[9];
    const float* Wm  = (const float*)d_in[10];
    const float* bm  = (const float*)d_in[11];
    const float* Wv  = (const float*)d_in[12];
    const float* bv  = (const float*)d_in[13];
    const float* Wt  = (const float*)d_in[14];
    const float* bt  = (const float*)d_in[15];
    const float* eps = (const float*)d_in[16];

    const int* e_src = ei;
    const int* e_dst = ei + N_EDGES;

    char* ws = (char*)d_ws;
    unsigned short* HA    = (unsigned short*)(ws + OFF_HA);
    unsigned short* HB    = (unsigned short*)(ws + OFF_HB);
    unsigned short* H0RES = (unsigned short*)(ws + OFF_H0RES);
    unsigned short* HMV   = (unsigned short*)(ws + OFF_HMV);
    unsigned short* W1t   = (unsigned short*)(ws + OFF_W1T);
    unsigned short* W2t   = (unsigned short*)(ws + OFF_W2T);
    unsigned short* W3t   = (unsigned short*)(ws + OFF_W3T);
    int2*  csrp    = (int2*)(ws + OFF_CSRP);
    int*   cnt     = (int*)(ws + OFF_CNT);
    int*   cnt2    = (int*)(ws + OFF_CNT2);
    int*   offs    = (int*)(ws + OFF_OFFS);
    float* dinv    = (float*)(ws + OFF_DINV);
    float* sumsA   = (float*)(ws + OFF_SUMSA);
    float* sumsB   = (float*)(ws + OFF_SUMSB);

    float* out_qz = (float*)d_out;
    float* out_qm = out_qz + N_NODES * ZDIM;
    float* out_qs = out_qm + N_NODES * ZDIM;
    float* out_t  = out_qs + N_NODES * ZDIM;

    const int MB = (N_NODES + 63) / 64;  // 782

    k_prep<<<1318, 256, 0, stream>>>(W1, W2, Wm, Wv, W1t, W2t, W3t,
                                     cnt, cnt2, sumsA, sumsB);
    k_count<<<(N_EDGES / 4 + 255) / 256, 256, 0, stream>>>(e_dst, cnt);
    k_scan<<<1, 1024, 0, stream>>>(cnt, offs, dinv);
    k_fill<<<(N_EDGES / 4 + 255) / 256, 256, 0, stream>>>(e_src, e_dst, offs, cnt2,
                                                          dinv, csrp);
    // layer 0
    k_gemm1m<<<MB, 256, 0, stream>>>(x, W1t, HA);
    k_aggs<<<AGG_GRID, 256, 0, stream>>>(HA, offs, csrp, dinv, HB, sumsA);
    // layer 1
    k_gemm2m<<<MB, 256, 0, stream>>>(HB, W2t, sumsA, g1, be1, H0RES, HA);
    k_aggs<<<AGG_GRID, 256, 0, stream>>>(HA, offs, csrp, dinv, HB, sumsB);
    // heads
    k_gemm3m<<<MB, 256, 0, stream>>>(HB, H0RES, sumsB, g2, be2, W3t, Wt, bt,
                                     HMV, out_t);
    k_aggfin5<<<AGG_GRID, 256, 0, stream>>>(HMV, offs, csrp, dinv, bm, bv, eps,
                                            out_qz, out_qm, out_qs);
}